// Round 3
// baseline (330.793 us; speedup 1.0000x reference)
//
#include <hip/hip_runtime.h>
#include <math.h>

#define NFAM  32
#define MREC  64
#define NCOPY 16
#define SPAD  65   // padded LDS stride: bank = (fam + col) % 32, spreads atomics

// ---------------------------------------------------------------------------
// Kernel 1: segmented sum of activity into per-(family, receptor) accumulators.
// Each block accumulates in LDS, then flushes with fp atomics into one of
// NCOPY global copies (contention: ~gridDim/NCOPY atomics per address).
// ---------------------------------------------------------------------------
__global__ __launch_bounds__(256, 8) void mmi_accum(
    const float* __restrict__ activity,
    const int*   __restrict__ family_ids,
    float*       __restrict__ gsum,   // [NCOPY][NFAM*MREC]
    int*         __restrict__ gcnt,   // [NCOPY][NFAM]
    int n_rows)
{
    __shared__ float ssum[NFAM * SPAD];
    __shared__ int   scnt[NFAM];
    const int tid = threadIdx.x;

    for (int i = tid; i < NFAM * SPAD; i += 256) ssum[i] = 0.0f;
    if (tid < NFAM) scnt[tid] = 0;
    __syncthreads();

    const int wave = tid >> 6;
    const int lane = tid & 63;
    const int sub  = lane >> 4;    // which row of the quad (0..3)
    const int k    = lane & 15;    // column-quad index (cols 4k..4k+3)

    const long long gw          = (long long)blockIdx.x * 4 + wave; // global wave id
    const long long total_waves = (long long)gridDim.x * 4;

    // Each wave streams contiguous 64-row chunks: 16 iterations x 4 rows.
    for (long long base = gw * 64; base < n_rows; base += total_waves * 64) {
        #pragma unroll 4
        for (int it = 0; it < 16; ++it) {
            long long row = base + it * 4 + sub;
            if (row < n_rows) {
                const float4 v =
                    *reinterpret_cast<const float4*>(activity + row * MREC + k * 4);
                int fam = family_ids[row];
                unsafeAtomicAdd(&ssum[fam * SPAD + k * 4 + 0], v.x);
                unsafeAtomicAdd(&ssum[fam * SPAD + k * 4 + 1], v.y);
                unsafeAtomicAdd(&ssum[fam * SPAD + k * 4 + 2], v.z);
                unsafeAtomicAdd(&ssum[fam * SPAD + k * 4 + 3], v.w);
                if (k == 0) atomicAdd(&scnt[fam], 1);
            }
        }
    }
    __syncthreads();

    // Flush block-local sums to one of NCOPY global copies.
    float* gs = gsum + (blockIdx.x % NCOPY) * (NFAM * MREC);
    int*   gc = gcnt + (blockIdx.x % NCOPY) * NFAM;
    for (int idx = tid; idx < NFAM * MREC; idx += 256) {
        int f = idx >> 6, m = idx & 63;
        unsafeAtomicAdd(&gs[idx], ssum[f * SPAD + m]);
    }
    if (tid < NFAM) atomicAdd(&gc[tid], scnt[tid]);
}

// ---------------------------------------------------------------------------
// Kernel 2: reduce the NCOPY copies, then compute
//   out = H(A|F) - H(A) = Sa - Sf/n_fam   (all in double; tiny work)
// where Sa = sum_m log(joint_pooled_m), Sf = sum_{f present} sum_m log(joint_fm)
// ---------------------------------------------------------------------------
__global__ void mmi_finalize(
    const float* __restrict__ gsum,
    const int*   __restrict__ gcnt,
    float*       __restrict__ out)
{
    __shared__ float red[NFAM * MREC];
    __shared__ int   rc[NFAM];
    const int tid = threadIdx.x;

    for (int idx = tid; idx < NFAM * MREC; idx += 256) {
        float s = 0.0f;
        for (int c = 0; c < NCOPY; ++c) s += gsum[c * (NFAM * MREC) + idx];
        red[idx] = s;
    }
    if (tid < NFAM) {
        int s = 0;
        for (int c = 0; c < NCOPY; ++c) s += gcnt[c * NFAM + tid];
        rc[tid] = s;
    }
    __syncthreads();

    if (tid < 64) {
        const int m = tid;
        double Ntot = 0.0;
        int nfam = 0;
        for (int f = 0; f < NFAM; ++f) { Ntot += (double)rc[f]; nfam += (rc[f] > 0); }

        // pooled entropy term for receptor m
        double T = 0.0;
        for (int f = 0; f < NFAM; ++f) T += (double)red[f * MREC + m];
        double mean = T / Ntot;
        double ja = (1.0 - mean) * (1.0 - mean) + mean * mean;
        double la = log(ja);

        // per-family entropy terms for receptor m
        double lf = 0.0;
        for (int f = 0; f < NFAM; ++f) {
            int c = rc[f];
            if (c > 0) {
                double mf = (double)red[f * MREC + m] / (double)c;
                double jf = (1.0 - mf) * (1.0 - mf) + mf * mf;
                lf += log(jf);
            }
        }

        // wave-wide (64-lane) sum reduction
        for (int off = 32; off > 0; off >>= 1) {
            la += __shfl_down(la, off, 64);
            lf += __shfl_down(lf, off, 64);
        }
        if (m == 0) {
            // result = h_a_given_f - h_a = (-Sf/nfam) - (-Sa) = Sa - Sf/nfam
            out[0] = (float)(la - lf / (double)nfam);
        }
    }
}

extern "C" void kernel_launch(void* const* d_in, const int* in_sizes, int n_in,
                              void* d_out, int out_size, void* d_ws, size_t ws_size,
                              hipStream_t stream) {
    const float* activity   = (const float*)d_in[0];
    const int*   family_ids = (const int*)d_in[1];
    float*       out        = (float*)d_out;

    const int n_rows = in_sizes[1];          // N = 524288 (family_ids count)

    float* gsum = (float*)d_ws;
    int*   gcnt = (int*)((char*)d_ws + (size_t)NCOPY * NFAM * MREC * sizeof(float));
    const size_t zbytes = (size_t)NCOPY * NFAM * MREC * sizeof(float)
                        + (size_t)NCOPY * NFAM * sizeof(int);

    hipMemsetAsync(d_ws, 0, zbytes, stream);

    const int grid = 2048;  // 8 blocks/CU on 256 CUs; covers 2048*4*64 = 524288 rows
    mmi_accum<<<grid, 256, 0, stream>>>(activity, family_ids, gsum, gcnt, n_rows);
    mmi_finalize<<<1, 256, 0, stream>>>(gsum, gcnt, out);
}